// Round 11
// baseline (2302.022 us; speedup 1.0000x reference)
//
#include <hip/hip_runtime.h>

#define HID 256
typedef unsigned short bfb;  // bf16 storage (raw bits)
typedef __attribute__((ext_vector_type(8))) short bf16x8_t;
typedef __attribute__((ext_vector_type(4))) float f32x4_t;

__device__ inline float bfb2f(bfb u) {
  unsigned v = ((unsigned)u) << 16;
  float f;
  __builtin_memcpy(&f, &v, 4);
  return f;
}
__device__ inline bfb f2bfb(float f) {
  unsigned v;
  __builtin_memcpy(&v, &f, 4);
  v += 0x7fff + ((v >> 16) & 1);
  return (bfb)(v >> 16);
}
__device__ inline float ldf(const bfb* p, size_t i) { return bfb2f(p[i]); }
__device__ inline void stf(bfb* p, size_t i, float v) { p[i] = f2bfb(v); }

__device__ inline void gld16(const void* g, void* l) {
  __builtin_amdgcn_global_load_lds(
      (const __attribute__((address_space(1))) void*)g,
      (__attribute__((address_space(3))) void*)l, 16, 0, 0);
}
__device__ inline f32x4_t mfma16(bf16x8_t a, bf16x8_t b, f32x4_t c) {
  return __builtin_amdgcn_mfma_f32_16x16x32_bf16(a, b, c, 0, 0, 0);
}

// ---------------- weight prep: [n][k] bf16 hi + lo per matrix ----------------
__global__ __launch_bounds__(256) void k_prep_w(
    const float* __restrict__ w1, const float* __restrict__ w2,
    bfb* __restrict__ wbuf, int n_layers) {
  int t = blockIdx.x * 256 + threadIdx.x;
  int total = n_layers * 2 * 65536;
  if (t >= total) return;
  int l = t / 131072;
  int rem = t - l * 131072;
  int which = rem >> 16;
  int e = rem & 65535;
  int n = e >> 8, k = e & 255;
  const float* src = (which ? w2 : w1) + (size_t)l * 65536;
  float v = src[k * 256 + n];
  bfb hi = f2bfb(v);
  bfb lo = f2bfb(v - bfb2f(hi));
  bfb* dst = wbuf + (size_t)l * 262144 + (size_t)which * 131072;
  dst[e] = hi;
  dst[65536 + e] = lo;
}

// ---------------- input projection ----------------
__global__ __launch_bounds__(256) void k_input_proj(
    const float* __restrict__ x, const float* __restrict__ W,
    const float* __restrict__ bias, bfb* __restrict__ z, int n_nodes) {
  __shared__ float sW[14 * HID];
  __shared__ float sx[64 * 14];
  for (int i = threadIdx.x; i < 14 * HID; i += blockDim.x) sW[i] = W[i];
  int c = threadIdx.x;
  float b = bias[c];
  int n0 = blockIdx.x * 64;
  int nmax = min(n0 + 64, n_nodes);
  int cnt = (nmax - n0) * 14;
  for (int i = threadIdx.x; i < cnt; i += blockDim.x) sx[i] = x[(size_t)n0 * 14 + i];
  __syncthreads();
  for (int n = n0; n < nmax; n++) {
    const float* xr = &sx[(n - n0) * 14];
    float acc = b;
#pragma unroll
    for (int k = 0; k < 14; k++) acc = fmaf(xr[k], sW[k * HID + c], acc);
    stf(z, (size_t)n * HID + c, acc);
  }
}

// ---------------- CSR build ----------------
__global__ __launch_bounds__(256) void k_hist(const int* __restrict__ dsts,
                                              int* deg, int ne) {
  int e = blockIdx.x * 256 + threadIdx.x;
  if (e < ne) atomicAdd(&deg[dsts[e]], 1);
}

__global__ __launch_bounds__(256) void k_scan1(const int* __restrict__ deg,
                                               int* bsum, int n) {
  __shared__ int sd[256];
  int i0 = blockIdx.x * 1024 + threadIdx.x * 4;
  int s = 0;
#pragma unroll
  for (int j = 0; j < 4; j++) {
    int i = i0 + j;
    if (i < n) s += deg[i];
  }
  sd[threadIdx.x] = s;
  __syncthreads();
  for (int off = 128; off > 0; off >>= 1) {
    if (threadIdx.x < off) sd[threadIdx.x] += sd[threadIdx.x + off];
    __syncthreads();
  }
  if (threadIdx.x == 0) bsum[blockIdx.x] = sd[0];
}

__global__ __launch_bounds__(256) void k_scan2(int* bsum, int nb) {
  __shared__ int sd[256];
  __shared__ int stot;
  int tid = threadIdx.x;
  int carry = 0;
  for (int base = 0; base < nb; base += 256) {
    int v = (base + tid < nb) ? bsum[base + tid] : 0;
    sd[tid] = v;
    __syncthreads();
    for (int off = 1; off < 256; off <<= 1) {
      int t = (tid >= off) ? sd[tid - off] : 0;
      __syncthreads();
      sd[tid] += t;
      __syncthreads();
    }
    int incl = sd[tid];
    if (base + tid < nb) bsum[base + tid] = carry + incl - v;
    if (tid == 255) stot = incl;
    __syncthreads();
    carry += stot;
    __syncthreads();
  }
}

__global__ __launch_bounds__(256) void k_scan3(const int* __restrict__ deg,
                                               const int* __restrict__ bsum,
                                               int* row_start, int* cursor, int n) {
  __shared__ int sd[256];
  int tid = threadIdx.x;
  int i0 = blockIdx.x * 1024 + tid * 4;
  int d[4];
  int s = 0;
#pragma unroll
  for (int j = 0; j < 4; j++) {
    int i = i0 + j;
    d[j] = (i < n) ? deg[i] : 0;
    s += d[j];
  }
  sd[tid] = s;
  __syncthreads();
  for (int off = 1; off < 256; off <<= 1) {
    int t = (tid >= off) ? sd[tid - off] : 0;
    __syncthreads();
    sd[tid] += t;
    __syncthreads();
  }
  int excl = sd[tid] - s + bsum[blockIdx.x];
#pragma unroll
  for (int j = 0; j < 4; j++) {
    int i = i0 + j;
    if (i < n) {
      row_start[i] = excl;
      cursor[i] = excl;
      if (i == n - 1) row_start[n] = excl + d[j];
      excl += d[j];
    }
  }
}

__global__ __launch_bounds__(256) void k_fill(
    const int* __restrict__ dsts, const int* __restrict__ srcs,
    const float* __restrict__ ea, int* cursor,
    int* __restrict__ src_s, float4* __restrict__ ea_s, int ne) {
  int e = blockIdx.x * 256 + threadIdx.x;
  if (e < ne) {
    int p = atomicAdd(&cursor[dsts[e]], 1);
    src_s[p] = srcs[e];
    ea_s[p] = make_float4(ea[(size_t)e * 3], ea[(size_t)e * 3 + 1],
                          ea[(size_t)e * 3 + 2], 0.0f);
  }
}

// ---------------- aggregate with on-the-fly BN+relu ----------------
template <int BN>
__global__ __launch_bounds__(256) void k_aggregate(
    const bfb* __restrict__ zin, const float4* __restrict__ ea_s,
    const int* __restrict__ src_s, const int* __restrict__ row_start,
    const float* __restrict__ eW, const float* __restrict__ eb,
    const float* __restrict__ stats, bfb* __restrict__ zout, int n_nodes) {
  __shared__ float sw0[HID], sw1[HID], sw2[HID], sb[HID], ssc[HID], ssh[HID];
  int tid = threadIdx.x;
  sw0[tid] = eW[tid];
  sw1[tid] = eW[HID + tid];
  sw2[tid] = eW[2 * HID + tid];
  sb[tid] = eb[tid];
  if (BN) {
    ssc[tid] = stats[2 * HID + tid];
    ssh[tid] = stats[3 * HID + tid];
  }
  __syncthreads();
  int w = tid >> 6, lane = tid & 63;
  int n = blockIdx.x * 4 + w;
  if (n >= n_nodes) return;
  int c0 = lane * 4;
  float w0[4], w1[4], w2[4], bb[4], sc[4], sh[4];
#pragma unroll
  for (int j = 0; j < 4; j++) {
    w0[j] = sw0[c0 + j]; w1[j] = sw1[c0 + j]; w2[j] = sw2[c0 + j]; bb[j] = sb[c0 + j];
    if (BN) { sc[j] = ssc[c0 + j]; sh[j] = ssh[c0 + j]; }
  }
  int i = row_start[n], i1 = row_start[n + 1];
  ushort4 hv = *(const ushort4*)&zin[(size_t)n * HID + c0];
  float hvf[4] = {bfb2f(hv.x), bfb2f(hv.y), bfb2f(hv.z), bfb2f(hv.w)};
  float acc[4];
#pragma unroll
  for (int j = 0; j < 4; j++)
    acc[j] = BN ? fmaxf(fmaf(hvf[j], sc[j], sh[j]), 0.0f) : hvf[j];
  for (; i + 2 <= i1; i += 2) {
    int s0 = src_s[i], s1 = src_s[i + 1];
    float4 a0 = ea_s[i];
    float4 a1 = ea_s[i + 1];
    ushort4 sv0 = *(const ushort4*)&zin[(size_t)s0 * HID + c0];
    ushort4 sv1 = *(const ushort4*)&zin[(size_t)s1 * HID + c0];
    float h0[4] = {bfb2f(sv0.x), bfb2f(sv0.y), bfb2f(sv0.z), bfb2f(sv0.w)};
    float h1[4] = {bfb2f(sv1.x), bfb2f(sv1.y), bfb2f(sv1.z), bfb2f(sv1.w)};
#pragma unroll
    for (int j = 0; j < 4; j++) {
      float e0 = fmaf(a0.x, w0[j], fmaf(a0.y, w1[j], fmaf(a0.z, w2[j], bb[j])));
      float e1 = fmaf(a1.x, w0[j], fmaf(a1.y, w1[j], fmaf(a1.z, w2[j], bb[j])));
      float g0 = BN ? fmaxf(fmaf(h0[j], sc[j], sh[j]), 0.0f) : h0[j];
      float g1 = BN ? fmaxf(fmaf(h1[j], sc[j], sh[j]), 0.0f) : h1[j];
      acc[j] += fmaxf(g0 + e0, 0.0f);
      acc[j] += fmaxf(g1 + e1, 0.0f);
    }
  }
  if (i < i1) {
    int s0 = src_s[i];
    float4 a0 = ea_s[i];
    ushort4 sv0 = *(const ushort4*)&zin[(size_t)s0 * HID + c0];
    float h0[4] = {bfb2f(sv0.x), bfb2f(sv0.y), bfb2f(sv0.z), bfb2f(sv0.w)};
#pragma unroll
    for (int j = 0; j < 4; j++) {
      float e0 = fmaf(a0.x, w0[j], fmaf(a0.y, w1[j], fmaf(a0.z, w2[j], bb[j])));
      float g0 = BN ? fmaxf(fmaf(h0[j], sc[j], sh[j]), 0.0f) : h0[j];
      acc[j] += fmaxf(g0 + e0, 0.0f);
    }
  }
  ushort4 o;
  o.x = f2bfb(acc[0]); o.y = f2bfb(acc[1]); o.z = f2bfb(acc[2]); o.w = f2bfb(acc[3]);
  *(ushort4*)&zout[(size_t)n * HID + c0] = o;
}

// ---------------- fused MLP v3: 8 waves, 32x64/wave, A staged in LDS ----------------
// 64-row tile, 512 threads (8 waves: wcol=wid>>1 0..3, wrow=wid&1).
// acc[2][4] = 32 VGPR/thread. A -> LDS once (global_load_lds, XOR-swizzled);
// W hi/lo per-lane from L2. t kept in LDS. 5 barriers/block.
__global__ __launch_bounds__(512, 4) void k_mlp3(
    const bfb* __restrict__ A, const bfb* __restrict__ wl,
    const float* __restrict__ b1, const float* __restrict__ b2,
    bfb* __restrict__ Cout, int Mreal, float* __restrict__ stats) {
  __shared__ __align__(16) bfb Ts[64 * 256];  // 32 KB
  const bfb* w1hi = wl;
  const bfb* w1lo = wl + 65536;
  const bfb* w2hi = wl + 131072;
  const bfb* w2lo = wl + 196608;
  int tid = threadIdx.x;
  int lane = tid & 63, wid = tid >> 6;
  int wcol = wid >> 1, wrow = wid & 1;
  int l15 = lane & 15, lq = lane >> 4;
  size_t bm = (size_t)blockIdx.x * 64;

  // ---- stage A[64][256] -> Ts (pre-swizzled source; dest linear) ----
  {
    int rrow = tid >> 5;  // 0..15 (+16 per pass); rrow&7 invariant under +16
    int sel = ((((tid & 31) << 4) ^ ((rrow & 7) << 4)) >> 1);
    const bfb* src = A + (bm + rrow) * 256 + sel;
#pragma unroll
    for (int i = 0; i < 4; i++)
      gld16(src + (size_t)i * 16 * 256, (char*)Ts + i * 8192 + wid * 1024);
  }
  __syncthreads();

  f32x4_t acc[2][4] = {};

  // ---- GEMM1: acc = A @ w1 (hi+lo); A-fragments from LDS ----
  {
    const bfb* Hb = w1hi + (size_t)(wcol * 64 + l15) * 256 + lq * 8;
    const bfb* Lb = w1lo + (size_t)(wcol * 64 + l15) * 256 + lq * 8;
#pragma unroll
    for (int kt = 0; kt < 8; kt++) {
      bf16x8_t af[2];
#pragma unroll
      for (int mi = 0; mi < 2; mi++) {
        int m = wrow * 32 + mi * 16 + l15;
        int byte = (m << 9) + ((kt * 64 + lq * 16) ^ ((m & 7) << 4));
        af[mi] = *(const bf16x8_t*)((const char*)Ts + byte);
      }
#pragma unroll
      for (int ni = 0; ni < 4; ni++) {
        bf16x8_t vh = *(const bf16x8_t*)(Hb + (size_t)ni * 16 * 256 + kt * 32);
        bf16x8_t vl = *(const bf16x8_t*)(Lb + (size_t)ni * 16 * 256 + kt * 32);
#pragma unroll
        for (int mi = 0; mi < 2; mi++) {
          acc[mi][ni] = mfma16(af[mi], vh, acc[mi][ni]);
          acc[mi][ni] = mfma16(af[mi], vl, acc[mi][ni]);
        }
      }
    }
  }
  __syncthreads();  // all A reads done before overwrite

  // ---- t = relu(acc + b1) -> Ts ----
#pragma unroll
  for (int ni = 0; ni < 4; ni++) {
    int col = wcol * 64 + ni * 16 + l15;
    float b = b1[col];
#pragma unroll
    for (int mi = 0; mi < 2; mi++)
#pragma unroll
      for (int r = 0; r < 4; r++) {
        int m = wrow * 32 + mi * 16 + lq * 4 + r;
        float v = fmaxf(acc[mi][ni][r] + b, 0.0f);
        int byte = (m << 9) + ((col * 2) ^ ((m & 7) << 4));
        *(bfb*)((char*)Ts + byte) = f2bfb(v);
        acc[mi][ni][r] = 0.0f;
      }
  }
  __syncthreads();

  // ---- GEMM2: acc = t @ w2 (hi+lo); t from LDS ----
  {
    const bfb* Hb = w2hi + (size_t)(wcol * 64 + l15) * 256 + lq * 8;
    const bfb* Lb = w2lo + (size_t)(wcol * 64 + l15) * 256 + lq * 8;
#pragma unroll
    for (int kt = 0; kt < 8; kt++) {
      bf16x8_t af[2];
#pragma unroll
      for (int mi = 0; mi < 2; mi++) {
        int m = wrow * 32 + mi * 16 + l15;
        int byte = (m << 9) + ((kt * 64 + lq * 16) ^ ((m & 7) << 4));
        af[mi] = *(const bf16x8_t*)((const char*)Ts + byte);
      }
#pragma unroll
      for (int ni = 0; ni < 4; ni++) {
        bf16x8_t vh = *(const bf16x8_t*)(Hb + (size_t)ni * 16 * 256 + kt * 32);
        bf16x8_t vl = *(const bf16x8_t*)(Lb + (size_t)ni * 16 * 256 + kt * 32);
#pragma unroll
        for (int mi = 0; mi < 2; mi++) {
          acc[mi][ni] = mfma16(af[mi], vh, acc[mi][ni]);
          acc[mi][ni] = mfma16(af[mi], vl, acc[mi][ni]);
        }
      }
    }
  }
  __syncthreads();  // t reads done; Ts reusable for output bounce

  // ---- epilogue: z = acc + b2 ; BN stats ; bounce via Ts ; coalesced out ----
  float ssum[4] = {}, ssq[4] = {};
#pragma unroll
  for (int ni = 0; ni < 4; ni++) {
    int col = wcol * 64 + ni * 16 + l15;
    float b = b2[col];
#pragma unroll
    for (int mi = 0; mi < 2; mi++)
#pragma unroll
      for (int r = 0; r < 4; r++) {
        int m = wrow * 32 + mi * 16 + lq * 4 + r;
        float v = acc[mi][ni][r] + b;
        int byte = (m << 9) + ((col * 2) ^ ((m & 7) << 4));
        *(bfb*)((char*)Ts + byte) = f2bfb(v);
        if ((int)bm + m < Mreal) {
          ssum[ni] += v;
          ssq[ni] = fmaf(v, v, ssq[ni]);
        }
      }
  }
#pragma unroll
  for (int ni = 0; ni < 4; ni++) {
    float s = ssum[ni], q = ssq[ni];
    s += __shfl_xor(s, 16); s += __shfl_xor(s, 32);
    q += __shfl_xor(q, 16); q += __shfl_xor(q, 32);
    if (lq == 0) {
      int col = wcol * 64 + ni * 16 + l15;
      atomicAdd(&stats[col], s);
      atomicAdd(&stats[HID + col], q);
    }
  }
  __syncthreads();
  {
    char* Cg = (char*)(Cout + bm * 256);
#pragma unroll
    for (int j = 0; j < 4; j++) {
      int b = j * 8192 + tid * 16;
      int row = b >> 9;
      int off = b & 511;
      float4 v = *(const float4*)((const char*)Ts + (row << 9) + (off ^ ((row & 7) << 4)));
      *(float4*)(Cg + b) = v;
    }
  }
}

// ---------------- BN finalize (also zeroes sums for next layer) ----------------
__global__ __launch_bounds__(256) void k_bn_finalize(
    float* stats, const float* __restrict__ gamma, const float* __restrict__ beta,
    float inv_n) {
  int c = threadIdx.x;
  float mu = stats[c] * inv_n;
  float var = stats[HID + c] * inv_n - mu * mu;
  float sc = gamma[c] * rsqrtf(var + 1e-5f);
  stats[2 * HID + c] = sc;
  stats[3 * HID + c] = beta[c] - mu * sc;
  stats[c] = 0.0f;
  stats[HID + c] = 0.0f;
}

// ---------------- pool (BN+relu on the fly) + divide ----------------
__global__ __launch_bounds__(256) void k_pool(
    const bfb* __restrict__ z, const float* __restrict__ stats,
    const int* __restrict__ batch, float* out, int n_nodes, int npb) {
  int c = threadIdx.x;
  float sc = stats[2 * HID + c];
  float sh = stats[3 * HID + c];
  int n0 = blockIdx.x * npb;
  int n1 = min(n0 + npb, n_nodes);
  if (n0 >= n1) return;
  int cur = batch[n0];
  float acc = 0.0f;
  for (int n = n0; n < n1; n++) {
    int g = batch[n];
    if (g != cur) {
      atomicAdd(&out[(size_t)cur * HID + c], acc);
      acc = 0.0f;
      cur = g;
    }
    acc += fmaxf(fmaf(ldf(z, (size_t)n * HID + c), sc, sh), 0.0f);
  }
  atomicAdd(&out[(size_t)cur * HID + c], acc);
}

__global__ __launch_bounds__(256) void k_div(
    float* out, const int* __restrict__ batch, int n_nodes) {
  int g = blockIdx.x;
  int lo = 0, hi = n_nodes;
  while (lo < hi) {
    int mid = (lo + hi) >> 1;
    if (batch[mid] < g) lo = mid + 1; else hi = mid;
  }
  int lo2 = lo, hi2 = n_nodes;
  while (lo2 < hi2) {
    int mid = (lo2 + hi2) >> 1;
    if (batch[mid] < g + 1) lo2 = mid + 1; else hi2 = mid;
  }
  float cnt = (float)(lo2 - lo);
  float inv = 1.0f / fmaxf(cnt, 1.0f);
  out[(size_t)g * HID + threadIdx.x] *= inv;
}

extern "C" void kernel_launch(void* const* d_in, const int* in_sizes, int n_in,
                              void* d_out, int out_size, void* d_ws, size_t ws_size,
                              hipStream_t stream) {
  const float* x = (const float*)d_in[0];
  const float* edge_attr = (const float*)d_in[1];
  const int* edge_index = (const int*)d_in[2];
  const int* batch = (const int*)d_in[3];
  const float* in_W = (const float*)d_in[4];
  const float* in_b = (const float*)d_in[5];
  const float* edge_W = (const float*)d_in[6];
  const float* edge_b = (const float*)d_in[7];
  const float* w1 = (const float*)d_in[8];
  const float* b1 = (const float*)d_in[9];
  const float* w2 = (const float*)d_in[10];
  const float* b2 = (const float*)d_in[11];
  const float* gamma = (const float*)d_in[12];
  const float* beta = (const float*)d_in[13];
  float* out = (float*)d_out;

  int n_nodes = in_sizes[3];
  int n_edges = in_sizes[1] / 3;
  int n_graphs = out_size / HID;
  int n_layers = in_sizes[7] / HID;

  const int* srcs = edge_index;
  const int* dsts = edge_index + n_edges;

  int Mp = ((n_nodes + 127) / 128) * 128;
  int Mt = (n_nodes + 63) / 64;
  size_t nhp = (size_t)Mp * HID;

  char* ws = (char*)d_ws;
  size_t off = 0;
  float* stats = (float*)(ws + off); off += 4096;
  bfb* wbuf = (bfb*)(ws + off); off += (size_t)n_layers * 262144 * 2;
  int* deg = (int*)(ws + off); off += ((size_t)n_nodes * 4 + 255) & ~255ull;
  int* row_start = (int*)(ws + off); off += ((size_t)(n_nodes + 1) * 4 + 255) & ~255ull;
  int* cursor = (int*)(ws + off); off += ((size_t)n_nodes * 4 + 255) & ~255ull;
  int* bsum = (int*)(ws + off); off += 4096;
  int* src_s = (int*)(ws + off); off += ((size_t)n_edges * 4 + 255) & ~255ull;
  float4* ea_s = (float4*)(ws + off); off += (size_t)n_edges * 16;
  bfb* P0 = (bfb*)(ws + off); off += nhp * 2;
  bfb* P1 = (bfb*)(ws + off);

  hipMemsetAsync(out, 0, (size_t)out_size * sizeof(float), stream);
  hipMemsetAsync(deg, 0, (size_t)n_nodes * 4, stream);
  hipMemsetAsync(stats, 0, 4096, stream);

  k_prep_w<<<(n_layers * 131072 + 255) / 256, 256, 0, stream>>>(w1, w2, wbuf, n_layers);
  k_input_proj<<<(n_nodes + 63) / 64, 256, 0, stream>>>(x, in_W, in_b, P0, n_nodes);

  int np = (n_nodes + 1023) / 1024;
  k_hist<<<(n_edges + 255) / 256, 256, 0, stream>>>(dsts, deg, n_edges);
  k_scan1<<<np, 256, 0, stream>>>(deg, bsum, n_nodes);
  k_scan2<<<1, 256, 0, stream>>>(bsum, np);
  k_scan3<<<np, 256, 0, stream>>>(deg, bsum, row_start, cursor, n_nodes);
  k_fill<<<(n_edges + 255) / 256, 256, 0, stream>>>(dsts, srcs, edge_attr, cursor,
                                                    src_s, ea_s, n_edges);

  bfb* cur = P0;  // raw pre-BN activations of current layer
  bfb* oth = P1;
  int gagg = (n_nodes + 3) / 4;
  for (int l = 0; l < n_layers; l++) {
    if (l == 0)
      k_aggregate<0><<<gagg, 256, 0, stream>>>(
          cur, ea_s, src_s, row_start, edge_W + (size_t)l * 3 * HID,
          edge_b + (size_t)l * HID, stats, oth, n_nodes);
    else
      k_aggregate<1><<<gagg, 256, 0, stream>>>(
          cur, ea_s, src_s, row_start, edge_W + (size_t)l * 3 * HID,
          edge_b + (size_t)l * HID, stats, oth, n_nodes);
    bfb* wl = wbuf + (size_t)l * 262144;
    // fused MLP: cur = (relu(oth@w1+b1))@w2 + b2, + BN sums (cur is dead input)
    k_mlp3<<<Mt, 512, 0, stream>>>(oth, wl, b1 + (size_t)l * HID,
                                   b2 + (size_t)l * HID, cur, n_nodes, stats);
    k_bn_finalize<<<1, 256, 0, stream>>>(stats, gamma + (size_t)l * HID,
                                         beta + (size_t)l * HID, 1.0f / (float)n_nodes);
    // cur already holds the new raw z; no swap needed.
  }

  k_pool<<<(n_nodes + 31) / 32, 256, 0, stream>>>(cur, stats, batch, out, n_nodes, 32);
  k_div<<<n_graphs, 256, 0, stream>>>(out, batch, n_nodes);
}

// Round 12
// 1165.087 us; speedup vs baseline: 1.9758x; 1.9758x over previous
//
#include <hip/hip_runtime.h>

#define HID 256
typedef unsigned short bfb;  // bf16 storage (raw bits)
typedef __attribute__((ext_vector_type(8))) short bf16x8_t;
typedef __attribute__((ext_vector_type(4))) float f32x4_t;

__device__ inline float bfb2f(bfb u) {
  unsigned v = ((unsigned)u) << 16;
  float f;
  __builtin_memcpy(&f, &v, 4);
  return f;
}
__device__ inline bfb f2bfb(float f) {
  unsigned v;
  __builtin_memcpy(&v, &f, 4);
  v += 0x7fff + ((v >> 16) & 1);
  return (bfb)(v >> 16);
}
__device__ inline float ldf(const bfb* p, size_t i) { return bfb2f(p[i]); }
__device__ inline void stf(bfb* p, size_t i, float v) { p[i] = f2bfb(v); }

__device__ inline void gld16(const void* g, void* l) {
  __builtin_amdgcn_global_load_lds(
      (const __attribute__((address_space(1))) void*)g,
      (__attribute__((address_space(3))) void*)l, 16, 0, 0);
}
__device__ inline f32x4_t mfma16(bf16x8_t a, bf16x8_t b, f32x4_t c) {
  return __builtin_amdgcn_mfma_f32_16x16x32_bf16(a, b, c, 0, 0, 0);
}

// ---------------- weight prep: [n][k] bf16 hi + lo per matrix ----------------
__global__ __launch_bounds__(256) void k_prep_w(
    const float* __restrict__ w1, const float* __restrict__ w2,
    bfb* __restrict__ wbuf, int n_layers) {
  int t = blockIdx.x * 256 + threadIdx.x;
  int total = n_layers * 2 * 65536;
  if (t >= total) return;
  int l = t / 131072;
  int rem = t - l * 131072;
  int which = rem >> 16;
  int e = rem & 65535;
  int n = e >> 8, k = e & 255;
  const float* src = (which ? w2 : w1) + (size_t)l * 65536;
  float v = src[k * 256 + n];
  bfb hi = f2bfb(v);
  bfb lo = f2bfb(v - bfb2f(hi));
  bfb* dst = wbuf + (size_t)l * 262144 + (size_t)which * 131072;
  dst[e] = hi;
  dst[65536 + e] = lo;
}

// ---------------- input projection ----------------
__global__ __launch_bounds__(256) void k_input_proj(
    const float* __restrict__ x, const float* __restrict__ W,
    const float* __restrict__ bias, bfb* __restrict__ z, int n_nodes) {
  __shared__ float sW[14 * HID];
  __shared__ float sx[64 * 14];
  for (int i = threadIdx.x; i < 14 * HID; i += blockDim.x) sW[i] = W[i];
  int c = threadIdx.x;
  float b = bias[c];
  int n0 = blockIdx.x * 64;
  int nmax = min(n0 + 64, n_nodes);
  int cnt = (nmax - n0) * 14;
  for (int i = threadIdx.x; i < cnt; i += blockDim.x) sx[i] = x[(size_t)n0 * 14 + i];
  __syncthreads();
  for (int n = n0; n < nmax; n++) {
    const float* xr = &sx[(n - n0) * 14];
    float acc = b;
#pragma unroll
    for (int k = 0; k < 14; k++) acc = fmaf(xr[k], sW[k * HID + c], acc);
    stf(z, (size_t)n * HID + c, acc);
  }
}

// ---------------- CSR build ----------------
__global__ __launch_bounds__(256) void k_hist(const int* __restrict__ dsts,
                                              int* deg, int ne) {
  int e = blockIdx.x * 256 + threadIdx.x;
  if (e < ne) atomicAdd(&deg[dsts[e]], 1);
}

__global__ __launch_bounds__(256) void k_scan1(const int* __restrict__ deg,
                                               int* bsum, int n) {
  __shared__ int sd[256];
  int i0 = blockIdx.x * 1024 + threadIdx.x * 4;
  int s = 0;
#pragma unroll
  for (int j = 0; j < 4; j++) {
    int i = i0 + j;
    if (i < n) s += deg[i];
  }
  sd[threadIdx.x] = s;
  __syncthreads();
  for (int off = 128; off > 0; off >>= 1) {
    if (threadIdx.x < off) sd[threadIdx.x] += sd[threadIdx.x + off];
    __syncthreads();
  }
  if (threadIdx.x == 0) bsum[blockIdx.x] = sd[0];
}

__global__ __launch_bounds__(256) void k_scan2(int* bsum, int nb) {
  __shared__ int sd[256];
  __shared__ int stot;
  int tid = threadIdx.x;
  int carry = 0;
  for (int base = 0; base < nb; base += 256) {
    int v = (base + tid < nb) ? bsum[base + tid] : 0;
    sd[tid] = v;
    __syncthreads();
    for (int off = 1; off < 256; off <<= 1) {
      int t = (tid >= off) ? sd[tid - off] : 0;
      __syncthreads();
      sd[tid] += t;
      __syncthreads();
    }
    int incl = sd[tid];
    if (base + tid < nb) bsum[base + tid] = carry + incl - v;
    if (tid == 255) stot = incl;
    __syncthreads();
    carry += stot;
    __syncthreads();
  }
}

__global__ __launch_bounds__(256) void k_scan3(const int* __restrict__ deg,
                                               const int* __restrict__ bsum,
                                               int* row_start, int* cursor, int n) {
  __shared__ int sd[256];
  int tid = threadIdx.x;
  int i0 = blockIdx.x * 1024 + tid * 4;
  int d[4];
  int s = 0;
#pragma unroll
  for (int j = 0; j < 4; j++) {
    int i = i0 + j;
    d[j] = (i < n) ? deg[i] : 0;
    s += d[j];
  }
  sd[tid] = s;
  __syncthreads();
  for (int off = 1; off < 256; off <<= 1) {
    int t = (tid >= off) ? sd[tid - off] : 0;
    __syncthreads();
    sd[tid] += t;
    __syncthreads();
  }
  int excl = sd[tid] - s + bsum[blockIdx.x];
#pragma unroll
  for (int j = 0; j < 4; j++) {
    int i = i0 + j;
    if (i < n) {
      row_start[i] = excl;
      cursor[i] = excl;
      if (i == n - 1) row_start[n] = excl + d[j];
      excl += d[j];
    }
  }
}

__global__ __launch_bounds__(256) void k_fill(
    const int* __restrict__ dsts, const int* __restrict__ srcs,
    const float* __restrict__ ea, int* cursor,
    int* __restrict__ src_s, float4* __restrict__ ea_s, int ne) {
  int e = blockIdx.x * 256 + threadIdx.x;
  if (e < ne) {
    int p = atomicAdd(&cursor[dsts[e]], 1);
    src_s[p] = srcs[e];
    ea_s[p] = make_float4(ea[(size_t)e * 3], ea[(size_t)e * 3 + 1],
                          ea[(size_t)e * 3 + 2], 0.0f);
  }
}

// ---------------- aggregate with on-the-fly BN+relu (2 gathers in flight) ----------------
template <int BN>
__global__ __launch_bounds__(256) void k_aggregate(
    const bfb* __restrict__ zin, const float4* __restrict__ ea_s,
    const int* __restrict__ src_s, const int* __restrict__ row_start,
    const float* __restrict__ eW, const float* __restrict__ eb,
    const float* __restrict__ stats, bfb* __restrict__ zout, int n_nodes) {
  __shared__ float sw0[HID], sw1[HID], sw2[HID], sb[HID], ssc[HID], ssh[HID];
  int tid = threadIdx.x;
  sw0[tid] = eW[tid];
  sw1[tid] = eW[HID + tid];
  sw2[tid] = eW[2 * HID + tid];
  sb[tid] = eb[tid];
  if (BN) {
    ssc[tid] = stats[2 * HID + tid];
    ssh[tid] = stats[3 * HID + tid];
  }
  __syncthreads();
  int w = tid >> 6, lane = tid & 63;
  int n = blockIdx.x * 4 + w;
  if (n >= n_nodes) return;
  int c0 = lane * 4;
  float w0[4], w1[4], w2[4], bb[4], sc[4], sh[4];
#pragma unroll
  for (int j = 0; j < 4; j++) {
    w0[j] = sw0[c0 + j]; w1[j] = sw1[c0 + j]; w2[j] = sw2[c0 + j]; bb[j] = sb[c0 + j];
    if (BN) { sc[j] = ssc[c0 + j]; sh[j] = ssh[c0 + j]; }
  }
  int i = row_start[n], i1 = row_start[n + 1];
  ushort4 hv = *(const ushort4*)&zin[(size_t)n * HID + c0];
  float hvf[4] = {bfb2f(hv.x), bfb2f(hv.y), bfb2f(hv.z), bfb2f(hv.w)};
  float acc[4];
#pragma unroll
  for (int j = 0; j < 4; j++)
    acc[j] = BN ? fmaxf(fmaf(hvf[j], sc[j], sh[j]), 0.0f) : hvf[j];
  for (; i + 2 <= i1; i += 2) {
    int s0 = src_s[i], s1 = src_s[i + 1];
    float4 a0 = ea_s[i];
    float4 a1 = ea_s[i + 1];
    ushort4 sv0 = *(const ushort4*)&zin[(size_t)s0 * HID + c0];
    ushort4 sv1 = *(const ushort4*)&zin[(size_t)s1 * HID + c0];
    float h0[4] = {bfb2f(sv0.x), bfb2f(sv0.y), bfb2f(sv0.z), bfb2f(sv0.w)};
    float h1[4] = {bfb2f(sv1.x), bfb2f(sv1.y), bfb2f(sv1.z), bfb2f(sv1.w)};
#pragma unroll
    for (int j = 0; j < 4; j++) {
      float e0 = fmaf(a0.x, w0[j], fmaf(a0.y, w1[j], fmaf(a0.z, w2[j], bb[j])));
      float e1 = fmaf(a1.x, w0[j], fmaf(a1.y, w1[j], fmaf(a1.z, w2[j], bb[j])));
      float g0 = BN ? fmaxf(fmaf(h0[j], sc[j], sh[j]), 0.0f) : h0[j];
      float g1 = BN ? fmaxf(fmaf(h1[j], sc[j], sh[j]), 0.0f) : h1[j];
      acc[j] += fmaxf(g0 + e0, 0.0f);
      acc[j] += fmaxf(g1 + e1, 0.0f);
    }
  }
  if (i < i1) {
    int s0 = src_s[i];
    float4 a0 = ea_s[i];
    ushort4 sv0 = *(const ushort4*)&zin[(size_t)s0 * HID + c0];
    float h0[4] = {bfb2f(sv0.x), bfb2f(sv0.y), bfb2f(sv0.z), bfb2f(sv0.w)};
#pragma unroll
    for (int j = 0; j < 4; j++) {
      float e0 = fmaf(a0.x, w0[j], fmaf(a0.y, w1[j], fmaf(a0.z, w2[j], bb[j])));
      float g0 = BN ? fmaxf(fmaf(h0[j], sc[j], sh[j]), 0.0f) : h0[j];
      acc[j] += fmaxf(g0 + e0, 0.0f);
    }
  }
  ushort4 o;
  o.x = f2bfb(acc[0]); o.y = f2bfb(acc[1]); o.z = f2bfb(acc[2]); o.w = f2bfb(acc[3]);
  *(ushort4*)&zout[(size_t)n * HID + c0] = o;
}

// ---------------- MFMA GEMM v2 (round-5, measured ~84us): 128x256 tile ----------------
// 512 threads (8 waves, 2 row x 4 col), BK=64 single-buffered, LDS-bounce epilogue.
template <int RELU, int STATS>
__global__ __launch_bounds__(512, 4) void k_gemm_mfma(
    const bfb* __restrict__ A, const bfb* __restrict__ Whi,
    const bfb* __restrict__ Wlo, const float* __restrict__ bias,
    bfb* __restrict__ C, int Mreal, float* __restrict__ stats) {
  __shared__ __align__(16) bfb smem[40960];  // 80 KB
  bfb* As = smem;           // [128][64] swizzled (16 KB)
  bfb* Bh = smem + 8192;    // [256][64] swizzled (32 KB)
  bfb* Bl = smem + 24576;   // [256][64] swizzled (32 KB)
  int tid = threadIdx.x;
  int lane = tid & 63, wid = tid >> 6;
  int wrow = wid >> 2, wcol = wid & 3;
  size_t bm = (size_t)blockIdx.x * 128;

  int srow = tid >> 3;                                     // 0..63 row in 64-row chunk
  int sel = (((tid & 7) * 16) ^ ((srow & 7) << 4)) >> 1;   // pre-swizzled source col
  int ldst = wid * 512;                                    // wave-uniform dest (elems)

  f32x4_t acc[4][4] = {};
  int sw = (lane & 7) << 4;
  int arow = wrow * 64 + (lane & 15);
  int brow = wcol * 64 + (lane & 15);
  int kgb = (lane >> 4) * 16;

  for (int kt = 0; kt < 4; kt++) {
    int k0 = kt * 64;
    const bfb* ab = A + bm * 256 + k0 + sel;
    const bfb* hb = Whi + k0 + sel;
    const bfb* lb = Wlo + k0 + sel;
#pragma unroll
    for (int i = 0; i < 2; i++)
      gld16(ab + (size_t)(i * 64 + srow) * 256, As + i * 4096 + ldst);
#pragma unroll
    for (int i = 0; i < 4; i++) {
      gld16(hb + (size_t)(i * 64 + srow) * 256, Bh + i * 4096 + ldst);
      gld16(lb + (size_t)(i * 64 + srow) * 256, Bl + i * 4096 + ldst);
    }
    __syncthreads();
#pragma unroll
    for (int ks = 0; ks < 2; ks++) {
      int kb = ks * 64 + kgb;
      bf16x8_t af[4];
#pragma unroll
      for (int mi = 0; mi < 4; mi++)
        af[mi] = *(const bf16x8_t*)((const char*)As + (arow + mi * 16) * 128 + (kb ^ sw));
#pragma unroll
      for (int ni = 0; ni < 4; ni++) {
        int pb = (brow + ni * 16) * 128 + (kb ^ sw);
        bf16x8_t bh = *(const bf16x8_t*)((const char*)Bh + pb);
        bf16x8_t bl = *(const bf16x8_t*)((const char*)Bl + pb);
#pragma unroll
        for (int mi = 0; mi < 4; mi++) {
          acc[mi][ni] = mfma16(af[mi], bh, acc[mi][ni]);
          acc[mi][ni] = mfma16(af[mi], bl, acc[mi][ni]);
        }
      }
    }
    __syncthreads();
  }
  // epilogue: bias(+relu)(+stats) -> LDS bounce -> coalesced float4 stores
  bfb* Cs = smem + 8192;  // [128][256] bf16 = 64 KB (reuses Bh+Bl)
  int crow0 = wrow * 64 + ((lane >> 4)) * 4;
  int ccol0 = wcol * 64 + (lane & 15);
  float ssum[4] = {}, ssq[4] = {};
#pragma unroll
  for (int ni = 0; ni < 4; ni++) {
    float b = bias[ccol0 + ni * 16];
#pragma unroll
    for (int mi = 0; mi < 4; mi++) {
#pragma unroll
      for (int r = 0; r < 4; r++) {
        int row = crow0 + mi * 16 + r;
        float v = acc[mi][ni][r] + b;
        if (RELU) v = fmaxf(v, 0.0f);
        int byte = (row * 512 + (ccol0 + ni * 16) * 2) ^ ((row & 15) << 4);
        *(bfb*)((char*)Cs + byte) = f2bfb(v);
        if (STATS && (int)bm + row < Mreal) {
          ssum[ni] += v;
          ssq[ni] = fmaf(v, v, ssq[ni]);
        }
      }
    }
  }
  if (STATS) {
#pragma unroll
    for (int ni = 0; ni < 4; ni++) {
      float s = ssum[ni], q = ssq[ni];
      s += __shfl_xor(s, 16); s += __shfl_xor(s, 32);
      q += __shfl_xor(q, 16); q += __shfl_xor(q, 32);
      if ((lane >> 4) == 0) {
        atomicAdd(&stats[ccol0 + ni * 16], s);
        atomicAdd(&stats[HID + ccol0 + ni * 16], q);
      }
    }
  }
  __syncthreads();
  {
    char* Cg = (char*)(C + bm * 256);
#pragma unroll
    for (int j = 0; j < 8; j++) {
      int b = j * 8192 + tid * 16;
      int row = b >> 9;
      int off = b & 511;
      float4 v = *(const float4*)((const char*)Cs + (row << 9) + (off ^ ((row & 15) << 4)));
      *(float4*)(Cg + b) = v;
    }
  }
}

// ---------------- BN finalize (also zeroes sums for next layer) ----------------
__global__ __launch_bounds__(256) void k_bn_finalize(
    float* stats, const float* __restrict__ gamma, const float* __restrict__ beta,
    float inv_n) {
  int c = threadIdx.x;
  float mu = stats[c] * inv_n;
  float var = stats[HID + c] * inv_n - mu * mu;
  float sc = gamma[c] * rsqrtf(var + 1e-5f);
  stats[2 * HID + c] = sc;
  stats[3 * HID + c] = beta[c] - mu * sc;
  stats[c] = 0.0f;
  stats[HID + c] = 0.0f;
}

// ---------------- pool (BN+relu on the fly) + divide ----------------
__global__ __launch_bounds__(256) void k_pool(
    const bfb* __restrict__ z, const float* __restrict__ stats,
    const int* __restrict__ batch, float* out, int n_nodes, int npb) {
  int c = threadIdx.x;
  float sc = stats[2 * HID + c];
  float sh = stats[3 * HID + c];
  int n0 = blockIdx.x * npb;
  int n1 = min(n0 + npb, n_nodes);
  if (n0 >= n1) return;
  int cur = batch[n0];
  float acc = 0.0f;
  for (int n = n0; n < n1; n++) {
    int g = batch[n];
    if (g != cur) {
      atomicAdd(&out[(size_t)cur * HID + c], acc);
      acc = 0.0f;
      cur = g;
    }
    acc += fmaxf(fmaf(ldf(z, (size_t)n * HID + c), sc, sh), 0.0f);
  }
  atomicAdd(&out[(size_t)cur * HID + c], acc);
}

__global__ __launch_bounds__(256) void k_div(
    float* out, const int* __restrict__ batch, int n_nodes) {
  int g = blockIdx.x;
  int lo = 0, hi = n_nodes;
  while (lo < hi) {
    int mid = (lo + hi) >> 1;
    if (batch[mid] < g) lo = mid + 1; else hi = mid;
  }
  int lo2 = lo, hi2 = n_nodes;
  while (lo2 < hi2) {
    int mid = (lo2 + hi2) >> 1;
    if (batch[mid] < g + 1) lo2 = mid + 1; else hi2 = mid;
  }
  float cnt = (float)(lo2 - lo);
  float inv = 1.0f / fmaxf(cnt, 1.0f);
  out[(size_t)g * HID + threadIdx.x] *= inv;
}

extern "C" void kernel_launch(void* const* d_in, const int* in_sizes, int n_in,
                              void* d_out, int out_size, void* d_ws, size_t ws_size,
                              hipStream_t stream) {
  const float* x = (const float*)d_in[0];
  const float* edge_attr = (const float*)d_in[1];
  const int* edge_index = (const int*)d_in[2];
  const int* batch = (const int*)d_in[3];
  const float* in_W = (const float*)d_in[4];
  const float* in_b = (const float*)d_in[5];
  const float* edge_W = (const float*)d_in[6];
  const float* edge_b = (const float*)d_in[7];
  const float* w1 = (const float*)d_in[8];
  const float* b1 = (const float*)d_in[9];
  const float* w2 = (const float*)d_in[10];
  const float* b2 = (const float*)d_in[11];
  const float* gamma = (const float*)d_in[12];
  const float* beta = (const float*)d_in[13];
  float* out = (float*)d_out;

  int n_nodes = in_sizes[3];
  int n_edges = in_sizes[1] / 3;
  int n_graphs = out_size / HID;
  int n_layers = in_sizes[7] / HID;

  const int* srcs = edge_index;
  const int* dsts = edge_index + n_edges;

  int Mp = ((n_nodes + 127) / 128) * 128;
  size_t nhp = (size_t)Mp * HID;

  char* ws = (char*)d_ws;
  size_t off = 0;
  float* stats = (float*)(ws + off); off += 4096;
  bfb* wbuf = (bfb*)(ws + off); off += (size_t)n_layers * 262144 * 2;
  int* deg = (int*)(ws + off); off += ((size_t)n_nodes * 4 + 255) & ~255ull;
  int* row_start = (int*)(ws + off); off += ((size_t)(n_nodes + 1) * 4 + 255) & ~255ull;
  int* cursor = (int*)(ws + off); off += ((size_t)n_nodes * 4 + 255) & ~255ull;
  int* bsum = (int*)(ws + off); off += 4096;
  int* src_s = (int*)(ws + off); off += ((size_t)n_edges * 4 + 255) & ~255ull;
  float4* ea_s = (float4*)(ws + off); off += (size_t)n_edges * 16;
  bfb* P0 = (bfb*)(ws + off); off += nhp * 2;
  bfb* P1 = (bfb*)(ws + off);

  hipMemsetAsync(out, 0, (size_t)out_size * sizeof(float), stream);
  hipMemsetAsync(deg, 0, (size_t)n_nodes * 4, stream);
  hipMemsetAsync(stats, 0, 4096, stream);

  k_prep_w<<<(n_layers * 131072 + 255) / 256, 256, 0, stream>>>(w1, w2, wbuf, n_layers);
  k_input_proj<<<(n_nodes + 63) / 64, 256, 0, stream>>>(x, in_W, in_b, P0, n_nodes);

  int np = (n_nodes + 1023) / 1024;
  k_hist<<<(n_edges + 255) / 256, 256, 0, stream>>>(dsts, deg, n_edges);
  k_scan1<<<np, 256, 0, stream>>>(deg, bsum, n_nodes);
  k_scan2<<<1, 256, 0, stream>>>(bsum, np);
  k_scan3<<<np, 256, 0, stream>>>(deg, bsum, row_start, cursor, n_nodes);
  k_fill<<<(n_edges + 255) / 256, 256, 0, stream>>>(dsts, srcs, edge_attr, cursor,
                                                    src_s, ea_s, n_edges);

  bfb* cur = P0;  // raw pre-BN activations of current layer
  bfb* oth = P1;
  int gagg = (n_nodes + 3) / 4;
  for (int l = 0; l < n_layers; l++) {
    if (l == 0)
      k_aggregate<0><<<gagg, 256, 0, stream>>>(
          cur, ea_s, src_s, row_start, edge_W + (size_t)l * 3 * HID,
          edge_b + (size_t)l * HID, stats, oth, n_nodes);
    else
      k_aggregate<1><<<gagg, 256, 0, stream>>>(
          cur, ea_s, src_s, row_start, edge_W + (size_t)l * 3 * HID,
          edge_b + (size_t)l * HID, stats, oth, n_nodes);
    bfb* wl = wbuf + (size_t)l * 262144;
    // GEMM1: cur = relu(oth @ w1 + b1)
    k_gemm_mfma<1, 0><<<Mp / 128, 512, 0, stream>>>(
        oth, wl, wl + 65536, b1 + (size_t)l * HID, cur, n_nodes, nullptr);
    // GEMM2: oth = cur @ w2 + b2 (+ fused BN sums)
    k_gemm_mfma<0, 1><<<Mp / 128, 512, 0, stream>>>(
        cur, wl + 131072, wl + 196608, b2 + (size_t)l * HID, oth, n_nodes, stats);
    k_bn_finalize<<<1, 256, 0, stream>>>(stats, gamma + (size_t)l * HID,
                                         beta + (size_t)l * HID, 1.0f / (float)n_nodes);
    bfb* t = cur; cur = oth; oth = t;  // cur now holds this layer's raw z
  }

  k_pool<<<(n_nodes + 31) / 32, 256, 0, stream>>>(cur, stats, batch, out, n_nodes, 32);
  k_div<<<n_graphs, 256, 0, stream>>>(out, batch, n_nodes);
}

// Round 13
// 1104.033 us; speedup vs baseline: 2.0851x; 1.0553x over previous
//
#include <hip/hip_runtime.h>

#define HID 256
typedef unsigned short bfb;  // f16 storage (raw bits)  [was bf16 in earlier rounds]
typedef _Float16 f16x8_t __attribute__((ext_vector_type(8)));
typedef __attribute__((ext_vector_type(4))) float f32x4_t;

// ---------- f16 bit helpers (storage-only; math in fp32) ----------
__device__ inline float bfb2f(bfb u) {
  _Float16 h;
  __builtin_memcpy(&h, &u, 2);
  return (float)h;
}
__device__ inline bfb f2bfb(float f) {
  _Float16 h = (_Float16)f;  // RTN-even via v_cvt_f16_f32
  bfb u;
  __builtin_memcpy(&u, &h, 2);
  return u;
}
__device__ inline float ldf(const bfb* p, size_t i) { return bfb2f(p[i]); }
__device__ inline void stf(bfb* p, size_t i, float v) { p[i] = f2bfb(v); }

__device__ inline void gld16(const void* g, void* l) {
  __builtin_amdgcn_global_load_lds(
      (const __attribute__((address_space(1))) void*)g,
      (__attribute__((address_space(3))) void*)l, 16, 0, 0);
}
__device__ inline f32x4_t mfma16(f16x8_t a, f16x8_t b, f32x4_t c) {
  return __builtin_amdgcn_mfma_f32_16x16x32_f16(a, b, c, 0, 0, 0);
}

// ---------------- weight prep: [n][k] f16, w1 then w2 per layer ----------------
__global__ __launch_bounds__(256) void k_prep_w(
    const float* __restrict__ w1, const float* __restrict__ w2,
    bfb* __restrict__ wbuf, int n_layers) {
  int t = blockIdx.x * 256 + threadIdx.x;
  int total = n_layers * 2 * 65536;
  if (t >= total) return;
  int l = t / 131072;
  int rem = t - l * 131072;
  int which = rem >> 16;
  int e = rem & 65535;
  int n = e >> 8, k = e & 255;
  const float* src = (which ? w2 : w1) + (size_t)l * 65536;
  bfb* dst = wbuf + (size_t)l * 131072 + (size_t)which * 65536;
  dst[e] = f2bfb(src[k * 256 + n]);
}

// ---------------- input projection ----------------
__global__ __launch_bounds__(256) void k_input_proj(
    const float* __restrict__ x, const float* __restrict__ W,
    const float* __restrict__ bias, bfb* __restrict__ z, int n_nodes) {
  __shared__ float sW[14 * HID];
  __shared__ float sx[64 * 14];
  for (int i = threadIdx.x; i < 14 * HID; i += blockDim.x) sW[i] = W[i];
  int c = threadIdx.x;
  float b = bias[c];
  int n0 = blockIdx.x * 64;
  int nmax = min(n0 + 64, n_nodes);
  int cnt = (nmax - n0) * 14;
  for (int i = threadIdx.x; i < cnt; i += blockDim.x) sx[i] = x[(size_t)n0 * 14 + i];
  __syncthreads();
  for (int n = n0; n < nmax; n++) {
    const float* xr = &sx[(n - n0) * 14];
    float acc = b;
#pragma unroll
    for (int k = 0; k < 14; k++) acc = fmaf(xr[k], sW[k * HID + c], acc);
    stf(z, (size_t)n * HID + c, acc);
  }
}

// ---------------- CSR build ----------------
__global__ __launch_bounds__(256) void k_hist(const int* __restrict__ dsts,
                                              int* deg, int ne) {
  int e = blockIdx.x * 256 + threadIdx.x;
  if (e < ne) atomicAdd(&deg[dsts[e]], 1);
}

__global__ __launch_bounds__(256) void k_scan1(const int* __restrict__ deg,
                                               int* bsum, int n) {
  __shared__ int sd[256];
  int i0 = blockIdx.x * 1024 + threadIdx.x * 4;
  int s = 0;
#pragma unroll
  for (int j = 0; j < 4; j++) {
    int i = i0 + j;
    if (i < n) s += deg[i];
  }
  sd[threadIdx.x] = s;
  __syncthreads();
  for (int off = 128; off > 0; off >>= 1) {
    if (threadIdx.x < off) sd[threadIdx.x] += sd[threadIdx.x + off];
    __syncthreads();
  }
  if (threadIdx.x == 0) bsum[blockIdx.x] = sd[0];
}

__global__ __launch_bounds__(256) void k_scan2(int* bsum, int nb) {
  __shared__ int sd[256];
  __shared__ int stot;
  int tid = threadIdx.x;
  int carry = 0;
  for (int base = 0; base < nb; base += 256) {
    int v = (base + tid < nb) ? bsum[base + tid] : 0;
    sd[tid] = v;
    __syncthreads();
    for (int off = 1; off < 256; off <<= 1) {
      int t = (tid >= off) ? sd[tid - off] : 0;
      __syncthreads();
      sd[tid] += t;
      __syncthreads();
    }
    int incl = sd[tid];
    if (base + tid < nb) bsum[base + tid] = carry + incl - v;
    if (tid == 255) stot = incl;
    __syncthreads();
    carry += stot;
    __syncthreads();
  }
}

__global__ __launch_bounds__(256) void k_scan3(const int* __restrict__ deg,
                                               const int* __restrict__ bsum,
                                               int* row_start, int* cursor, int n) {
  __shared__ int sd[256];
  int tid = threadIdx.x;
  int i0 = blockIdx.x * 1024 + tid * 4;
  int d[4];
  int s = 0;
#pragma unroll
  for (int j = 0; j < 4; j++) {
    int i = i0 + j;
    d[j] = (i < n) ? deg[i] : 0;
    s += d[j];
  }
  sd[tid] = s;
  __syncthreads();
  for (int off = 1; off < 256; off <<= 1) {
    int t = (tid >= off) ? sd[tid - off] : 0;
    __syncthreads();
    sd[tid] += t;
    __syncthreads();
  }
  int excl = sd[tid] - s + bsum[blockIdx.x];
#pragma unroll
  for (int j = 0; j < 4; j++) {
    int i = i0 + j;
    if (i < n) {
      row_start[i] = excl;
      cursor[i] = excl;
      if (i == n - 1) row_start[n] = excl + d[j];
      excl += d[j];
    }
  }
}

__global__ __launch_bounds__(256) void k_fill(
    const int* __restrict__ dsts, const int* __restrict__ srcs,
    const float* __restrict__ ea, int* cursor,
    int* __restrict__ src_s, float4* __restrict__ ea_s, int ne) {
  int e = blockIdx.x * 256 + threadIdx.x;
  if (e < ne) {
    int p = atomicAdd(&cursor[dsts[e]], 1);
    src_s[p] = srcs[e];
    ea_s[p] = make_float4(ea[(size_t)e * 3], ea[(size_t)e * 3 + 1],
                          ea[(size_t)e * 3 + 2], 0.0f);
  }
}

// ---------------- aggregate with on-the-fly BN+relu (2 gathers in flight) ----------------
template <int BN>
__global__ __launch_bounds__(256) void k_aggregate(
    const bfb* __restrict__ zin, const float4* __restrict__ ea_s,
    const int* __restrict__ src_s, const int* __restrict__ row_start,
    const float* __restrict__ eW, const float* __restrict__ eb,
    const float* __restrict__ stats, bfb* __restrict__ zout, int n_nodes) {
  __shared__ float sw0[HID], sw1[HID], sw2[HID], sb[HID], ssc[HID], ssh[HID];
  int tid = threadIdx.x;
  sw0[tid] = eW[tid];
  sw1[tid] = eW[HID + tid];
  sw2[tid] = eW[2 * HID + tid];
  sb[tid] = eb[tid];
  if (BN) {
    ssc[tid] = stats[2 * HID + tid];
    ssh[tid] = stats[3 * HID + tid];
  }
  __syncthreads();
  int w = tid >> 6, lane = tid & 63;
  int n = blockIdx.x * 4 + w;
  if (n >= n_nodes) return;
  int c0 = lane * 4;
  float w0[4], w1[4], w2[4], bb[4], sc[4], sh[4];
#pragma unroll
  for (int j = 0; j < 4; j++) {
    w0[j] = sw0[c0 + j]; w1[j] = sw1[c0 + j]; w2[j] = sw2[c0 + j]; bb[j] = sb[c0 + j];
    if (BN) { sc[j] = ssc[c0 + j]; sh[j] = ssh[c0 + j]; }
  }
  int i = row_start[n], i1 = row_start[n + 1];
  ushort4 hv = *(const ushort4*)&zin[(size_t)n * HID + c0];
  float hvf[4] = {bfb2f(hv.x), bfb2f(hv.y), bfb2f(hv.z), bfb2f(hv.w)};
  float acc[4];
#pragma unroll
  for (int j = 0; j < 4; j++)
    acc[j] = BN ? fmaxf(fmaf(hvf[j], sc[j], sh[j]), 0.0f) : hvf[j];
  for (; i + 2 <= i1; i += 2) {
    int s0 = src_s[i], s1 = src_s[i + 1];
    float4 a0 = ea_s[i];
    float4 a1 = ea_s[i + 1];
    ushort4 sv0 = *(const ushort4*)&zin[(size_t)s0 * HID + c0];
    ushort4 sv1 = *(const ushort4*)&zin[(size_t)s1 * HID + c0];
    float h0[4] = {bfb2f(sv0.x), bfb2f(sv0.y), bfb2f(sv0.z), bfb2f(sv0.w)};
    float h1[4] = {bfb2f(sv1.x), bfb2f(sv1.y), bfb2f(sv1.z), bfb2f(sv1.w)};
#pragma unroll
    for (int j = 0; j < 4; j++) {
      float e0 = fmaf(a0.x, w0[j], fmaf(a0.y, w1[j], fmaf(a0.z, w2[j], bb[j])));
      float e1 = fmaf(a1.x, w0[j], fmaf(a1.y, w1[j], fmaf(a1.z, w2[j], bb[j])));
      float g0 = BN ? fmaxf(fmaf(h0[j], sc[j], sh[j]), 0.0f) : h0[j];
      float g1 = BN ? fmaxf(fmaf(h1[j], sc[j], sh[j]), 0.0f) : h1[j];
      acc[j] += fmaxf(g0 + e0, 0.0f);
      acc[j] += fmaxf(g1 + e1, 0.0f);
    }
  }
  if (i < i1) {
    int s0 = src_s[i];
    float4 a0 = ea_s[i];
    ushort4 sv0 = *(const ushort4*)&zin[(size_t)s0 * HID + c0];
    float h0[4] = {bfb2f(sv0.x), bfb2f(sv0.y), bfb2f(sv0.z), bfb2f(sv0.w)};
#pragma unroll
    for (int j = 0; j < 4; j++) {
      float e0 = fmaf(a0.x, w0[j], fmaf(a0.y, w1[j], fmaf(a0.z, w2[j], bb[j])));
      float g0 = BN ? fmaxf(fmaf(h0[j], sc[j], sh[j]), 0.0f) : h0[j];
      acc[j] += fmaxf(g0 + e0, 0.0f);
    }
  }
  ushort4 o;
  o.x = f2bfb(acc[0]); o.y = f2bfb(acc[1]); o.z = f2bfb(acc[2]); o.w = f2bfb(acc[3]);
  *(ushort4*)&zout[(size_t)n * HID + c0] = o;
}

// ---------------- MFMA GEMM (f16, single-precision weights): 128x256 tile ----------------
// 512 threads (8 waves, 2 row x 4 col), BK=64 single-buffered, LDS-bounce epilogue.
// LDS 64 KB: As [128][64] (16 KB) + Bw [256][64] (32 KB); epilogue reuses all as Cs.
template <int RELU, int STATS>
__global__ __launch_bounds__(512, 4) void k_gemm_mfma(
    const bfb* __restrict__ A, const bfb* __restrict__ W,
    const float* __restrict__ bias, bfb* __restrict__ C,
    int Mreal, float* __restrict__ stats) {
  __shared__ __align__(16) bfb smem[32768];  // 64 KB
  bfb* As = smem;           // [128][64] swizzled (16 KB)
  bfb* Bw = smem + 8192;    // [256][64] swizzled (32 KB)
  int tid = threadIdx.x;
  int lane = tid & 63, wid = tid >> 6;
  int wrow = wid >> 2, wcol = wid & 3;
  size_t bm = (size_t)blockIdx.x * 128;

  int srow = tid >> 3;                                     // 0..63 row in 64-row chunk
  int sel = (((tid & 7) * 16) ^ ((srow & 7) << 4)) >> 1;   // pre-swizzled source col
  int ldst = wid * 512;                                    // wave-uniform dest (elems)

  f32x4_t acc[4][4] = {};
  int sw = (lane & 7) << 4;
  int arow = wrow * 64 + (lane & 15);
  int brow = wcol * 64 + (lane & 15);
  int kgb = (lane >> 4) * 16;

  for (int kt = 0; kt < 4; kt++) {
    int k0 = kt * 64;
    const bfb* ab = A + bm * 256 + k0 + sel;
    const bfb* wb = W + k0 + sel;
#pragma unroll
    for (int i = 0; i < 2; i++)
      gld16(ab + (size_t)(i * 64 + srow) * 256, As + i * 4096 + ldst);
#pragma unroll
    for (int i = 0; i < 4; i++)
      gld16(wb + (size_t)(i * 64 + srow) * 256, Bw + i * 4096 + ldst);
    __syncthreads();
#pragma unroll
    for (int ks = 0; ks < 2; ks++) {
      int kb = ks * 64 + kgb;
      f16x8_t af[4];
#pragma unroll
      for (int mi = 0; mi < 4; mi++)
        af[mi] = *(const f16x8_t*)((const char*)As + (arow + mi * 16) * 128 + (kb ^ sw));
#pragma unroll
      for (int ni = 0; ni < 4; ni++) {
        int pb = (brow + ni * 16) * 128 + (kb ^ sw);
        f16x8_t bw = *(const f16x8_t*)((const char*)Bw + pb);
#pragma unroll
        for (int mi = 0; mi < 4; mi++)
          acc[mi][ni] = mfma16(af[mi], bw, acc[mi][ni]);
      }
    }
    __syncthreads();
  }
  // epilogue: bias(+relu)(+stats) -> LDS bounce -> coalesced float4 stores
  char* Cs = (char*)smem;  // [128][256] f16 = 64 KB (reuses As+Bw)
  int crow0 = wrow * 64 + (lane >> 4) * 4;
  int ccol0 = wcol * 64 + (lane & 15);
  float ssum[4] = {}, ssq[4] = {};
#pragma unroll
  for (int ni = 0; ni < 4; ni++) {
    float b = bias[ccol0 + ni * 16];
#pragma unroll
    for (int mi = 0; mi < 4; mi++) {
#pragma unroll
      for (int r = 0; r < 4; r++) {
        int row = crow0 + mi * 16 + r;
        float v = acc[mi][ni][r] + b;
        if (RELU) v = fmaxf(v, 0.0f);
        int byte = (row * 512 + (ccol0 + ni * 16) * 2) ^ ((row & 15) << 4);
        *(bfb*)(Cs + byte) = f2bfb(v);
        if (STATS && (int)bm + row < Mreal) {
          ssum[ni] += v;
          ssq[ni] = fmaf(v, v, ssq[ni]);
        }
      }
    }
  }
  if (STATS) {
#pragma unroll
    for (int ni = 0; ni < 4; ni++) {
      float s = ssum[ni], q = ssq[ni];
      s += __shfl_xor(s, 16); s += __shfl_xor(s, 32);
      q += __shfl_xor(q, 16); q += __shfl_xor(q, 32);
      if ((lane >> 4) == 0) {
        atomicAdd(&stats[ccol0 + ni * 16], s);
        atomicAdd(&stats[HID + ccol0 + ni * 16], q);
      }
    }
  }
  __syncthreads();
  {
    char* Cg = (char*)(C + bm * 256);
#pragma unroll
    for (int j = 0; j < 8; j++) {
      int b = j * 8192 + tid * 16;
      int row = b >> 9;
      int off = b & 511;
      float4 v = *(const float4*)(Cs + (row << 9) + (off ^ ((row & 15) << 4)));
      *(float4*)(Cg + b) = v;
    }
  }
}

// ---------------- BN finalize (also zeroes sums for next layer) ----------------
__global__ __launch_bounds__(256) void k_bn_finalize(
    float* stats, const float* __restrict__ gamma, const float* __restrict__ beta,
    float inv_n) {
  int c = threadIdx.x;
  float mu = stats[c] * inv_n;
  float var = stats[HID + c] * inv_n - mu * mu;
  float sc = gamma[c] * rsqrtf(var + 1e-5f);
  stats[2 * HID + c] = sc;
  stats[3 * HID + c] = beta[c] - mu * sc;
  stats[c] = 0.0f;
  stats[HID + c] = 0.0f;
}

// ---------------- pool (BN+relu on the fly) + divide ----------------
__global__ __launch_bounds__(256) void k_pool(
    const bfb* __restrict__ z, const float* __restrict__ stats,
    const int* __restrict__ batch, float* out, int n_nodes, int npb) {
  int c = threadIdx.x;
  float sc = stats[2 * HID + c];
  float sh = stats[3 * HID + c];
  int n0 = blockIdx.x * npb;
  int n1 = min(n0 + npb, n_nodes);
  if (n0 >= n1) return;
  int cur = batch[n0];
  float acc = 0.0f;
  for (int n = n0; n < n1; n++) {
    int g = batch[n];
    if (g != cur) {
      atomicAdd(&out[(size_t)cur * HID + c], acc);
      acc = 0.0f;
      cur = g;
    }
    acc += fmaxf(fmaf(ldf(z, (size_t)n * HID + c), sc, sh), 0.0f);
  }
  atomicAdd(&out[(size_t)cur * HID + c], acc);
}

__global__ __launch_bounds__(256) void k_div(
    float* out, const int* __restrict__ batch, int n_nodes) {
  int g = blockIdx.x;
  int lo = 0, hi = n_nodes;
  while (lo < hi) {
    int mid = (lo + hi) >> 1;
    if (batch[mid] < g) lo = mid + 1; else hi = mid;
  }
  int lo2 = lo, hi2 = n_nodes;
  while (lo2 < hi2) {
    int mid = (lo2 + hi2) >> 1;
    if (batch[mid] < g + 1) lo2 = mid + 1; else hi2 = mid;
  }
  float cnt = (float)(lo2 - lo);
  float inv = 1.0f / fmaxf(cnt, 1.0f);
  out[(size_t)g * HID + threadIdx.x] *= inv;
}

extern "C" void kernel_launch(void* const* d_in, const int* in_sizes, int n_in,
                              void* d_out, int out_size, void* d_ws, size_t ws_size,
                              hipStream_t stream) {
  const float* x = (const float*)d_in[0];
  const float* edge_attr = (const float*)d_in[1];
  const int* edge_index = (const int*)d_in[2];
  const int* batch = (const int*)d_in[3];
  const float* in_W = (const float*)d_in[4];
  const float* in_b = (const float*)d_in[5];
  const float* edge_W = (const float*)d_in[6];
  const float* edge_b = (const float*)d_in[7];
  const float* w1 = (const float*)d_in[8];
  const float* b1 = (const float*)d_in[9];
  const float* w2 = (const float*)d_in[10];
  const float* b2 = (const float*)d_in[11];
  const float* gamma = (const float*)d_in[12];
  const float* beta = (const float*)d_in[13];
  float* out = (float*)d_out;

  int n_nodes = in_sizes[3];
  int n_edges = in_sizes[1] / 3;
  int n_graphs = out_size / HID;
  int n_layers = in_sizes[7] / HID;

  const int* srcs = edge_index;
  const int* dsts = edge_index + n_edges;

  int Mp = ((n_nodes + 127) / 128) * 128;
  size_t nhp = (size_t)Mp * HID;

  char* ws = (char*)d_ws;
  size_t off = 0;
  float* stats = (float*)(ws + off); off += 4096;
  bfb* wbuf = (bfb*)(ws + off); off += (size_t)n_layers * 131072 * 2;  // f16, w1+w2
  int* deg = (int*)(ws + off); off += ((size_t)n_nodes * 4 + 255) & ~255ull;
  int* row_start = (int*)(ws + off); off += ((size_t)(n_nodes + 1) * 4 + 255) & ~255ull;
  int* cursor = (int*)(ws + off); off += ((size_t)n_nodes * 4 + 255) & ~255ull;
  int* bsum = (int*)(ws + off); off += 4096;
  int* src_s = (int*)(ws + off); off += ((size_t)n_edges * 4 + 255) & ~255ull;
  float4* ea_s = (float4*)(ws + off); off += (size_t)n_edges * 16;
  bfb* P0 = (bfb*)(ws + off); off += nhp * 2;
  bfb* P1 = (bfb*)(ws + off);

  hipMemsetAsync(out, 0, (size_t)out_size * sizeof(float), stream);
  hipMemsetAsync(deg, 0, (size_t)n_nodes * 4, stream);
  hipMemsetAsync(stats, 0, 4096, stream);

  k_prep_w<<<(n_layers * 131072 + 255) / 256, 256, 0, stream>>>(w1, w2, wbuf, n_layers);
  k_input_proj<<<(n_nodes + 63) / 64, 256, 0, stream>>>(x, in_W, in_b, P0, n_nodes);

  int np = (n_nodes + 1023) / 1024;
  k_hist<<<(n_edges + 255) / 256, 256, 0, stream>>>(dsts, deg, n_edges);
  k_scan1<<<np, 256, 0, stream>>>(deg, bsum, n_nodes);
  k_scan2<<<1, 256, 0, stream>>>(bsum, np);
  k_scan3<<<np, 256, 0, stream>>>(deg, bsum, row_start, cursor, n_nodes);
  k_fill<<<(n_edges + 255) / 256, 256, 0, stream>>>(dsts, srcs, edge_attr, cursor,
                                                    src_s, ea_s, n_edges);

  bfb* cur = P0;  // raw pre-BN activations of current layer
  bfb* oth = P1;
  int gagg = (n_nodes + 3) / 4;
  for (int l = 0; l < n_layers; l++) {
    if (l == 0)
      k_aggregate<0><<<gagg, 256, 0, stream>>>(
          cur, ea_s, src_s, row_start, edge_W + (size_t)l * 3 * HID,
          edge_b + (size_t)l * HID, stats, oth, n_nodes);
    else
      k_aggregate<1><<<gagg, 256, 0, stream>>>(
          cur, ea_s, src_s, row_start, edge_W + (size_t)l * 3 * HID,
          edge_b + (size_t)l * HID, stats, oth, n_nodes);
    bfb* wl = wbuf + (size_t)l * 131072;
    // GEMM1: cur = relu(oth @ w1 + b1)
    k_gemm_mfma<1, 0><<<Mp / 128, 512, 0, stream>>>(
        oth, wl, b1 + (size_t)l * HID, cur, n_nodes, nullptr);
    // GEMM2: oth = cur @ w2 + b2 (+ fused BN sums)
    k_gemm_mfma<0, 1><<<Mp / 128, 512, 0, stream>>>(
        cur, wl + 65536, b2 + (size_t)l * HID, oth, n_nodes, stats);
    k_bn_finalize<<<1, 256, 0, stream>>>(stats, gamma + (size_t)l * HID,
                                         beta + (size_t)l * HID, 1.0f / (float)n_nodes);
    bfb* t = cur; cur = oth; oth = t;  // cur now holds this layer's raw z
  }

  k_pool<<<(n_nodes + 31) / 32, 256, 0, stream>>>(cur, stats, batch, out, n_nodes, 32);
  k_div<<<n_graphs, 256, 0, stream>>>(out, batch, n_nodes);
}